// Round 3
// baseline (316.364 us; speedup 1.0000x reference)
//
#include <hip/hip_runtime.h>

#define TOKENS 8192
#define IN_F   4096
#define OUT_F  4096

#define BM 256
#define BN 256
#define BK 64
#define NT (IN_F / BK)   // 64 K-tiles

typedef __attribute__((ext_vector_type(4))) float  f32x4;
typedef __attribute__((ext_vector_type(4))) int    i32x4;
typedef __attribute__((ext_vector_type(8))) unsigned short u16x8;
typedef __attribute__((ext_vector_type(8))) __bf16 bf16x8;

typedef const __attribute__((address_space(1))) void gas_void;
typedef __attribute__((address_space(3))) void las_void;

__device__ __forceinline__ unsigned short f2bf(float f) {
    unsigned int u = __builtin_bit_cast(unsigned int, f);
    u += 0x7fffu + ((u >> 16) & 1u);   // round-to-nearest-even
    return (unsigned short)(u >> 16);
}

__global__ __launch_bounds__(256) void cvt_x_kernel(const float* __restrict__ x,
                                                    unsigned short* __restrict__ xb) {
    const int t = blockIdx.x * 256 + threadIdx.x;
    const f32x4* p = (const f32x4*)x + (size_t)t * 2;
    f32x4 a = p[0], b = p[1];
    u16x8 o;
#pragma unroll
    for (int j = 0; j < 4; ++j) { o[j] = f2bf(a[j]); o[4 + j] = f2bf(b[j]); }
    ((u16x8*)xb)[t] = o;
}

__global__ __launch_bounds__(256) void deq_w_kernel(const int* __restrict__ tern,
                                                    const float* __restrict__ scales,
                                                    unsigned short* __restrict__ wb) {
    const int t = blockIdx.x * 256 + threadIdx.x;
    const float s = scales[t >> 4];
    const i32x4* p = (const i32x4*)tern + (size_t)t * 2;
    i32x4 a = p[0], b = p[1];
    u16x8 o;
#pragma unroll
    for (int j = 0; j < 4; ++j) {
        o[j]     = f2bf((float)a[j] * s);
        o[4 + j] = f2bf((float)b[j] * s);
    }
    ((u16x8*)wb)[t] = o;
}

// ---------------------------------------------------------------------------
// C[M][N] = A[M][K] * B[N][K]^T, bf16 in / fp32 out.
// 256x256 tile, BK=64, 8 waves (2M x 4N), per-wave output 128x64.
// 4 phases/K-tile, READ-AHEAD: each QUAD's ds_reads are issued one phase
// early; counted lgkmcnt(12) gates so reads overlap prior MFMA (T3+T4 lgkm
// analog). Counted vmcnt(4) once per tile. T2 swizzle, T5 setprio.
// Read/issue schedule (QUADs: Q1=(a0-3,b01) Q2=(a4-7,b23) Q3=(a0-3,b23)
// Q4=(a4-7,b01)):
//   t.P4 (after vmcnt+barrier, buf(t+1) valid): read t+1 a0-3 (pre-QUAD),
//        b01 (post-QUAD, avoids WAR with Q4's b01 use)
//   t.P1: read t a4-7,b23; stage t+1.H2B; gate lgkm(12) -> Q1 done
//   t.P2: stage t+1.H3B; gate lgkm(0) -> Q2 done (all buf(t) reads complete)
//   t.P3: stage t+2.H0A into live buf (safe per P2 gate); Q3 from regs
//   t.P4: stage t+2.H1A; vmcnt(4) drains all of t+1; Q4 from regs
// ---------------------------------------------------------------------------

#define QUAD(MI0, NI0)                                                         \
  do {                                                                         \
    _Pragma("unroll") for (int mi = 0; mi < 4; ++mi)                           \
      _Pragma("unroll") for (int ni = 0; ni < 2; ++ni)                         \
        _Pragma("unroll") for (int kk = 0; kk < 2; ++kk)                       \
          acc[(MI0)+mi][(NI0)+ni] = __builtin_amdgcn_mfma_f32_16x16x32_bf16(   \
              a[(MI0)+mi][kk], b[(NI0)+ni][kk], acc[(MI0)+mi][(NI0)+ni],0,0,0);\
  } while (0)

__global__ __launch_bounds__(512, 2) void gemm_bt_kernel(
        const unsigned short* __restrict__ A,
        const unsigned short* __restrict__ B,
        float* __restrict__ C) {
    __shared__ __align__(16) unsigned short As[2 * 256 * 64];
    __shared__ __align__(16) unsigned short Bs[2 * 256 * 64];

    const int tid  = threadIdx.x;
    const int wave = tid >> 6;
    const int lane = tid & 63;
    const int wm   = wave >> 2;        // 0-1
    const int wn   = wave & 3;         // 0-3
    const int lg   = lane >> 4;        // 0-3
    const int lr   = lane & 15;        // 0-15

    // XCD-aware swizzle (512 blocks, 512%8==0 -> bijective)
    int bid = blockIdx.x;
    bid = (bid & 7) * (512 >> 3) + (bid >> 3);
    const int bm = bid >> 4;           // 0-31
    const int bn = bid & 15;           // 0-15

    const size_t a_row0 = (size_t)bm * BM;
    const size_t b_row0 = (size_t)bn * BN;

    // stage one half-tile (128 rows x 64 cols bf16 = 16 KiB): 2 loads/thread.
    // LDS dest linear; global source pre-swizzled (rule #21 both-sides).
    auto stage_half = [&](int buf, int half, int which, int k0) {
        const unsigned short* G = which ? B : A;
        const size_t grow0 = (which ? b_row0 : a_row0) + (size_t)half * 128;
        unsigned short* T = (which ? Bs : As) + buf * 16384 + half * 8192;
#pragma unroll
        for (int i = 0; i < 2; ++i) {
            const int qe    = (i * 512 + tid) * 8;          // elem offset in half
            const int row_h = qe >> 6;                      // 0..127
            const int cswz  = (qe & 63) ^ ((row_h & 7) << 3);
            const unsigned short* src = G + (grow0 + row_h) * IN_F + k0 + cswz;
            unsigned short* dst = T + (i * 512 + (wave << 6)) * 8; // wave-uniform
            __builtin_amdgcn_global_load_lds((gas_void*)src, (las_void*)dst, 16, 0, 0);
        }
    };

    f32x4  acc[8][4] = {};
    bf16x8 a[8][2], b[4][2];

    const int sw   = (lr & 7) << 3;
    const int ksw0 = (lg * 8) ^ sw;
    const int ksw1 = (32 + lg * 8) ^ sw;
    const int arow = (wm * 128 + lr) * 64;
    const int brow = (wn * 64  + lr) * 64;

    auto rdA = [&](int mi, int base) {
        a[mi][0] = *(const bf16x8*)&As[base + arow + mi * 1024 + ksw0];
        a[mi][1] = *(const bf16x8*)&As[base + arow + mi * 1024 + ksw1];
    };
    auto rdB = [&](int ni, int base) {
        b[ni][0] = *(const bf16x8*)&Bs[base + brow + ni * 1024 + ksw0];
        b[ni][1] = *(const bf16x8*)&Bs[base + brow + ni * 1024 + ksw1];
    };

    // ---- prologue: tile0 fully + tile1 A-halves; drain tile0, keep 4 in
    // flight; then issue t=0's Q1 reads (a0-3, b01).
    stage_half(0, 0, 0, 0);  stage_half(0, 1, 0, 0);
    stage_half(0, 0, 1, 0);  stage_half(0, 1, 1, 0);
    stage_half(1, 0, 0, BK); stage_half(1, 1, 0, BK);
    asm volatile("s_waitcnt vmcnt(4)" ::: "memory");
    __builtin_amdgcn_sched_barrier(0);
    __builtin_amdgcn_s_barrier();
    rdA(0, 0); rdA(1, 0); rdA(2, 0); rdA(3, 0);
    rdB(0, 0); rdB(1, 0);

    for (int t = 0; t < NT; ++t) {
        const int buf   = t & 1;
        const int base  = buf * 16384;
        const int bufn  = buf ^ 1;
        const int nbase = bufn * 16384;

        // ---- P1: issue Q2 reads; stage t+1.H2B; gate lgkm(12) (Q1 done)
        rdA(4, base); rdA(5, base); rdA(6, base); rdA(7, base);
        rdB(2, base); rdB(3, base);
        if (t + 1 < NT) stage_half(bufn, 0, 1, (t + 1) * BK);
        __builtin_amdgcn_s_barrier();
        asm volatile("s_waitcnt lgkmcnt(12)" ::: "memory");
        __builtin_amdgcn_sched_barrier(0);
        __builtin_amdgcn_s_setprio(1);
        QUAD(0, 0);
        __builtin_amdgcn_s_setprio(0);
        __builtin_amdgcn_s_barrier();

        // ---- P2: stage t+1.H3B; gate lgkm(0) (Q2 done; all buf(t) reads done)
        if (t + 1 < NT) stage_half(bufn, 1, 1, (t + 1) * BK);
        __builtin_amdgcn_s_barrier();
        asm volatile("s_waitcnt lgkmcnt(0)" ::: "memory");
        __builtin_amdgcn_sched_barrier(0);
        __builtin_amdgcn_s_setprio(1);
        QUAD(4, 2);
        __builtin_amdgcn_s_setprio(0);
        __builtin_amdgcn_s_barrier();

        // ---- P3: stage t+2.H0A into freed live buf; Q3 from regs
        if (t + 2 < NT) stage_half(buf, 0, 0, (t + 2) * BK);
        __builtin_amdgcn_s_barrier();
        __builtin_amdgcn_s_setprio(1);
        QUAD(0, 2);
        __builtin_amdgcn_s_setprio(0);
        __builtin_amdgcn_s_barrier();

        // ---- P4: stage t+2.H1A; counted vmcnt; then read-ahead t+1.Q1
        if (t + 2 < NT) {
            stage_half(buf, 1, 0, (t + 2) * BK);
            asm volatile("s_waitcnt vmcnt(4)" ::: "memory");
        } else if (t + 1 < NT) {
            asm volatile("s_waitcnt vmcnt(0)" ::: "memory");
        }
        __builtin_amdgcn_sched_barrier(0);
        __builtin_amdgcn_s_barrier();
        if (t + 1 < NT) { rdA(0, nbase); rdA(1, nbase); rdA(2, nbase); rdA(3, nbase); }
        __builtin_amdgcn_s_setprio(1);
        QUAD(4, 0);
        __builtin_amdgcn_s_setprio(0);
        if (t + 1 < NT) { rdB(0, nbase); rdB(1, nbase); }
        __builtin_amdgcn_s_barrier();
    }

    // ---- epilogue: C/D layout col=lane&15, row=(lane>>4)*4+j
    float* Cp = C + (a_row0 + wm * 128) * (size_t)OUT_F + b_row0 + wn * 64;
#pragma unroll
    for (int mi = 0; mi < 8; ++mi)
#pragma unroll
        for (int ni = 0; ni < 4; ++ni)
#pragma unroll
            for (int j = 0; j < 4; ++j)
                Cp[(size_t)(mi * 16 + lg * 4 + j) * OUT_F + ni * 16 + lr] = acc[mi][ni][j];
}

extern "C" void kernel_launch(void* const* d_in, const int* in_sizes, int n_in,
                              void* d_out, int out_size, void* d_ws, size_t ws_size,
                              hipStream_t stream) {
    const float* x      = (const float*)d_in[0];
    const int*   tern   = (const int*)d_in[1];
    const float* scales = (const float*)d_in[2];

    unsigned short* xb = (unsigned short*)d_ws;
    unsigned short* wb = xb + (size_t)TOKENS * IN_F;

    cvt_x_kernel<<<TOKENS * IN_F / 8 / 256, 256, 0, stream>>>(x, xb);
    deq_w_kernel<<<OUT_F * IN_F / 8 / 256, 256, 0, stream>>>(tern, scales, wb);

    dim3 grid((TOKENS / BM) * (OUT_F / BN));   // 32*16 = 512
    gemm_bt_kernel<<<grid, 512, 0, stream>>>(xb, wb, (float*)d_out);
}

// Round 4
// 314.204 us; speedup vs baseline: 1.0069x; 1.0069x over previous
//
#include <hip/hip_runtime.h>

#define TOKENS 8192
#define IN_F   4096
#define OUT_F  4096

#define BM 256
#define BN 256
#define BK 64
#define NT (IN_F / BK)   // 64 K-tiles

typedef __attribute__((ext_vector_type(4))) float  f32x4;
typedef __attribute__((ext_vector_type(4))) int    i32x4;
typedef __attribute__((ext_vector_type(8))) unsigned short u16x8;
typedef __attribute__((ext_vector_type(8))) __bf16 bf16x8;

typedef const __attribute__((address_space(1))) void gas_void;
typedef __attribute__((address_space(3))) void las_void;

__device__ __forceinline__ unsigned short f2bf(float f) {
    unsigned int u = __builtin_bit_cast(unsigned int, f);
    u += 0x7fffu + ((u >> 16) & 1u);   // round-to-nearest-even
    return (unsigned short)(u >> 16);
}

__global__ __launch_bounds__(256) void cvt_x_kernel(const float* __restrict__ x,
                                                    unsigned short* __restrict__ xb) {
    const int t = blockIdx.x * 256 + threadIdx.x;
    const f32x4* p = (const f32x4*)x + (size_t)t * 2;
    f32x4 a = p[0], b = p[1];
    u16x8 o;
#pragma unroll
    for (int j = 0; j < 4; ++j) { o[j] = f2bf(a[j]); o[4 + j] = f2bf(b[j]); }
    ((u16x8*)xb)[t] = o;
}

__global__ __launch_bounds__(256) void deq_w_kernel(const int* __restrict__ tern,
                                                    const float* __restrict__ scales,
                                                    unsigned short* __restrict__ wb) {
    const int t = blockIdx.x * 256 + threadIdx.x;
    const float s = scales[t >> 4];
    const i32x4* p = (const i32x4*)tern + (size_t)t * 2;
    i32x4 a = p[0], b = p[1];
    u16x8 o;
#pragma unroll
    for (int j = 0; j < 4; ++j) {
        o[j]     = f2bf((float)a[j] * s);
        o[4 + j] = f2bf((float)b[j] * s);
    }
    ((u16x8*)wb)[t] = o;
}

// ---------------------------------------------------------------------------
// C[M][N] = A[M][K] * B[N][K]^T, bf16 in / fp32 out.
// 256x256 tile, BK=64, 8 waves (2M x 4N), per-wave output 128x64.
// m201-faithful phase structure: per phase {in-phase ds_reads; 1 half-tile
// stage; [lgkm(8) if 12 reads]; barrier; lgkm(0); setprio; 16 MFMA; barrier}.
// Reads balanced 12/8/4/0 via quadrant order Q(0,0) Q(4,0) Q(4,2) Q(0,2):
//   P1: read a0-3,b01 (12); QUAD(0,0)
//   P2: read a4-7     (8);  QUAD(4,0)   [b01 persists]
//   P3: read b23      (4);  QUAD(4,2)   [a4-7 persist]
//   P4: read none;          QUAD(0,2)   [a0-3, b23 persist]
// Staging (tile t, buf c=t&1): P1: t+1.H2B->c^1 | P2: t+1.H3B->c^1 |
//   P3: t+2.H0A->c (all As[c] reads done by end-P2) | P4: t+2.H1A->c, then
//   vmcnt(4): drains all 4 half-tiles of t+1, leaves t+2's 2 A-halves in
//   flight (never 0 mid-loop). T2 both-sides swizzle; T5 setprio.
// ---------------------------------------------------------------------------

#define QUAD(MI0, NI0)                                                         \
  do {                                                                         \
    _Pragma("unroll") for (int mi = 0; mi < 4; ++mi)                           \
      _Pragma("unroll") for (int ni = 0; ni < 2; ++ni)                         \
        _Pragma("unroll") for (int kk = 0; kk < 2; ++kk)                       \
          acc[(MI0)+mi][(NI0)+ni] = __builtin_amdgcn_mfma_f32_16x16x32_bf16(   \
              a[(MI0)+mi][kk], b[(NI0)+ni][kk], acc[(MI0)+mi][(NI0)+ni],0,0,0);\
  } while (0)

__global__ __launch_bounds__(512, 2) void gemm_bt_kernel(
        const unsigned short* __restrict__ A,
        const unsigned short* __restrict__ B,
        float* __restrict__ C) {
    __shared__ __align__(16) unsigned short As[2 * 256 * 64];
    __shared__ __align__(16) unsigned short Bs[2 * 256 * 64];

    const int tid  = threadIdx.x;
    const int wave = tid >> 6;
    const int lane = tid & 63;
    const int wm   = wave >> 2;        // 0-1
    const int wn   = wave & 3;         // 0-3
    const int lg   = lane >> 4;        // 0-3
    const int lr   = lane & 15;        // 0-15

    // XCD-aware swizzle (512 blocks, 512%8==0 -> bijective)
    int bid = blockIdx.x;
    bid = (bid & 7) * (512 >> 3) + (bid >> 3);
    const int bm = bid >> 4;           // 0-31
    const int bn = bid & 15;           // 0-15

    const size_t a_row0 = (size_t)bm * BM;
    const size_t b_row0 = (size_t)bn * BN;

    // stage one half-tile (128 rows x 64 cols bf16 = 16 KiB): 2 loads/thread.
    // LDS dest linear; global source pre-swizzled (rule #21 both-sides).
    auto stage_half = [&](int buf, int half, int which, int k0) {
        const unsigned short* G = which ? B : A;
        const size_t grow0 = (which ? b_row0 : a_row0) + (size_t)half * 128;
        unsigned short* T = (which ? Bs : As) + buf * 16384 + half * 8192;
#pragma unroll
        for (int i = 0; i < 2; ++i) {
            const int qe    = (i * 512 + tid) * 8;          // elem offset in half
            const int row_h = qe >> 6;                      // 0..127
            const int cswz  = (qe & 63) ^ ((row_h & 7) << 3);
            const unsigned short* src = G + (grow0 + row_h) * IN_F + k0 + cswz;
            unsigned short* dst = T + (i * 512 + (wave << 6)) * 8; // wave-uniform
            __builtin_amdgcn_global_load_lds((gas_void*)src, (las_void*)dst, 16, 0, 0);
        }
    };

    f32x4  acc[8][4] = {};
    bf16x8 a[8][2], b[4][2];

    const int sw   = (lr & 7) << 3;
    const int ksw0 = (lg * 8) ^ sw;
    const int ksw1 = (32 + lg * 8) ^ sw;
    const int arow = (wm * 128 + lr) * 64;
    const int brow = (wn * 64  + lr) * 64;

    auto rdA = [&](int mi, int base) {
        a[mi][0] = *(const bf16x8*)&As[base + arow + mi * 1024 + ksw0];
        a[mi][1] = *(const bf16x8*)&As[base + arow + mi * 1024 + ksw1];
    };
    auto rdB = [&](int ni, int base) {
        b[ni][0] = *(const bf16x8*)&Bs[base + brow + ni * 1024 + ksw0];
        b[ni][1] = *(const bf16x8*)&Bs[base + brow + ni * 1024 + ksw1];
    };

    // ---- prologue: tile0 fully + tile1 A-halves; drain tile0, keep 4 in flight
    stage_half(0, 0, 0, 0);  stage_half(0, 1, 0, 0);
    stage_half(0, 0, 1, 0);  stage_half(0, 1, 1, 0);
    stage_half(1, 0, 0, BK); stage_half(1, 1, 0, BK);
    asm volatile("s_waitcnt vmcnt(4)" ::: "memory");
    __builtin_amdgcn_sched_barrier(0);
    __builtin_amdgcn_s_barrier();

    for (int t = 0; t < NT; ++t) {
        const int buf  = t & 1;
        const int base = buf * 16384;
        const int bufn = buf ^ 1;

        // ---- P1: read a0-3,b01 (12); stage t+1.H2B; QUAD(0,0)
        rdA(0, base); rdA(1, base); rdA(2, base); rdA(3, base);
        rdB(0, base); rdB(1, base);
        if (t + 1 < NT) stage_half(bufn, 0, 1, (t + 1) * BK);
        asm volatile("s_waitcnt lgkmcnt(8)" ::: "memory");   // early-drain hint
        __builtin_amdgcn_s_barrier();
        asm volatile("s_waitcnt lgkmcnt(0)" ::: "memory");
        __builtin_amdgcn_sched_barrier(0);
        __builtin_amdgcn_s_setprio(1);
        QUAD(0, 0);
        __builtin_amdgcn_s_setprio(0);
        __builtin_amdgcn_s_barrier();

        // ---- P2: read a4-7 (8); stage t+1.H3B; QUAD(4,0)
        rdA(4, base); rdA(5, base); rdA(6, base); rdA(7, base);
        if (t + 1 < NT) stage_half(bufn, 1, 1, (t + 1) * BK);
        __builtin_amdgcn_s_barrier();
        asm volatile("s_waitcnt lgkmcnt(0)" ::: "memory");
        __builtin_amdgcn_sched_barrier(0);
        __builtin_amdgcn_s_setprio(1);
        QUAD(4, 0);
        __builtin_amdgcn_s_setprio(0);
        __builtin_amdgcn_s_barrier();

        // ---- P3: read b23 (4); stage t+2.H0A into freed live buf; QUAD(4,2)
        rdB(2, base); rdB(3, base);
        if (t + 2 < NT) stage_half(buf, 0, 0, (t + 2) * BK);
        __builtin_amdgcn_s_barrier();
        asm volatile("s_waitcnt lgkmcnt(0)" ::: "memory");
        __builtin_amdgcn_sched_barrier(0);
        __builtin_amdgcn_s_setprio(1);
        QUAD(4, 2);
        __builtin_amdgcn_s_setprio(0);
        __builtin_amdgcn_s_barrier();

        // ---- P4: no reads; stage t+2.H1A; counted vmcnt; QUAD(0,2)
        if (t + 2 < NT) {
            stage_half(buf, 1, 0, (t + 2) * BK);
            asm volatile("s_waitcnt vmcnt(4)" ::: "memory");
        } else if (t + 1 < NT) {
            asm volatile("s_waitcnt vmcnt(0)" ::: "memory");
        }
        __builtin_amdgcn_sched_barrier(0);
        __builtin_amdgcn_s_barrier();
        __builtin_amdgcn_s_setprio(1);
        QUAD(0, 2);
        __builtin_amdgcn_s_setprio(0);
        __builtin_amdgcn_s_barrier();
    }

    // ---- epilogue: C/D layout col=lane&15, row=(lane>>4)*4+j
    float* Cp = C + (a_row0 + wm * 128) * (size_t)OUT_F + b_row0 + wn * 64;
#pragma unroll
    for (int mi = 0; mi < 8; ++mi)
#pragma unroll
        for (int ni = 0; ni < 4; ++ni)
#pragma unroll
            for (int j = 0; j < 4; ++j)
                Cp[(size_t)(mi * 16 + lg * 4 + j) * OUT_F + ni * 16 + lr] = acc[mi][ni][j];
}

extern "C" void kernel_launch(void* const* d_in, const int* in_sizes, int n_in,
                              void* d_out, int out_size, void* d_ws, size_t ws_size,
                              hipStream_t stream) {
    const float* x      = (const float*)d_in[0];
    const int*   tern   = (const int*)d_in[1];
    const float* scales = (const float*)d_in[2];

    unsigned short* xb = (unsigned short*)d_ws;
    unsigned short* wb = xb + (size_t)TOKENS * IN_F;

    cvt_x_kernel<<<TOKENS * IN_F / 8 / 256, 256, 0, stream>>>(x, xb);
    deq_w_kernel<<<OUT_F * IN_F / 8 / 256, 256, 0, stream>>>(tern, scales, wb);

    dim3 grid((TOKENS / BM) * (OUT_F / BN));   // 32*16 = 512
    gemm_bt_kernel<<<grid, 512, 0, stream>>>(xb, wb, (float*)d_out);
}

// Round 5
// 273.780 us; speedup vs baseline: 1.1555x; 1.1476x over previous
//
#include <hip/hip_runtime.h>

#define TOKENS 8192
#define IN_F   4096
#define OUT_F  4096

#define BM 256
#define BN 256
#define BK 64
#define NT (IN_F / BK)   // 64 K-tiles

typedef __attribute__((ext_vector_type(4))) float  f32x4;
typedef __attribute__((ext_vector_type(4))) int    i32x4;
typedef __attribute__((ext_vector_type(8))) unsigned short u16x8;
typedef __attribute__((ext_vector_type(8))) __bf16 bf16x8;

typedef const __attribute__((address_space(1))) void gas_void;
typedef __attribute__((address_space(3))) void las_void;

__device__ __forceinline__ unsigned short f2bf(float f) {
    unsigned int u = __builtin_bit_cast(unsigned int, f);
    u += 0x7fffu + ((u >> 16) & 1u);   // round-to-nearest-even
    return (unsigned short)(u >> 16);
}

__global__ __launch_bounds__(256) void cvt_x_kernel(const float* __restrict__ x,
                                                    unsigned short* __restrict__ xb) {
    const int t = blockIdx.x * 256 + threadIdx.x;
    const f32x4* p = (const f32x4*)x + (size_t)t * 2;
    f32x4 a = p[0], b = p[1];
    u16x8 o;
#pragma unroll
    for (int j = 0; j < 4; ++j) { o[j] = f2bf(a[j]); o[4 + j] = f2bf(b[j]); }
    ((u16x8*)xb)[t] = o;
}

__global__ __launch_bounds__(256) void deq_w_kernel(const int* __restrict__ tern,
                                                    const float* __restrict__ scales,
                                                    unsigned short* __restrict__ wb) {
    const int t = blockIdx.x * 256 + threadIdx.x;
    const float s = scales[t >> 4];
    const i32x4* p = (const i32x4*)tern + (size_t)t * 2;
    i32x4 a = p[0], b = p[1];
    u16x8 o;
#pragma unroll
    for (int j = 0; j < 4; ++j) {
        o[j]     = f2bf((float)a[j] * s);
        o[4 + j] = f2bf((float)b[j] * s);
    }
    ((u16x8*)wb)[t] = o;
}

// ---------------------------------------------------------------------------
// C[M][N] = A[M][K] * B[N][K]^T, bf16 in / fp32 out.
// 256x256 tile, BK=64, 8 waves (2M x 4N), per-wave output 128x64.
// r5: two-barrier K-loop with compiler-scheduled fine-grained lgkm waits.
//   Region 1: read a0-3,b01 | stage t+1.H2B | Q(0,0) | read a4-7 |
//             stage t+1.H3B | Q(4,0) | read b23
//   BARRIER #1 (all As[cur] reads consumed -> safe to overwrite As[cur])
//   Region 2: stage t+2.H0A->cur | Q(4,2) | stage t+2.H1A->cur | Q(0,2) |
//             vmcnt(4)  (drains t+1's 4 half-tiles; t+2's 2 A-halves in flight)
//   BARRIER #2 (staged halves visible to all waves)
// sched_barrier(0) flanks every s_barrier: reg-only MFMAs + their auto-waits
// must not sink across (rule 18), else As-overwrite races the reads.
// T2 both-sides swizzle (conflict-free, verified r2); T4 counted vmcnt; T5.
// ---------------------------------------------------------------------------

#define QUAD(MI0, NI0)                                                         \
  do {                                                                         \
    __builtin_amdgcn_s_setprio(1);                                             \
    _Pragma("unroll") for (int mi = 0; mi < 4; ++mi)                           \
      _Pragma("unroll") for (int ni = 0; ni < 2; ++ni)                         \
        _Pragma("unroll") for (int kk = 0; kk < 2; ++kk)                       \
          acc[(MI0)+mi][(NI0)+ni] = __builtin_amdgcn_mfma_f32_16x16x32_bf16(   \
              a[(MI0)+mi][kk], b[(NI0)+ni][kk], acc[(MI0)+mi][(NI0)+ni],0,0,0);\
    __builtin_amdgcn_s_setprio(0);                                             \
  } while (0)

__global__ __launch_bounds__(512, 2) void gemm_bt_kernel(
        const unsigned short* __restrict__ A,
        const unsigned short* __restrict__ B,
        float* __restrict__ C) {
    __shared__ __align__(16) unsigned short As[2 * 256 * 64];
    __shared__ __align__(16) unsigned short Bs[2 * 256 * 64];

    const int tid  = threadIdx.x;
    const int wave = tid >> 6;
    const int lane = tid & 63;
    const int wm   = wave >> 2;        // 0-1
    const int wn   = wave & 3;         // 0-3
    const int lg   = lane >> 4;        // 0-3
    const int lr   = lane & 15;        // 0-15

    // XCD-aware swizzle (512 blocks, 512%8==0 -> bijective)
    int bid = blockIdx.x;
    bid = (bid & 7) * (512 >> 3) + (bid >> 3);
    const int bm = bid >> 4;           // 0-31
    const int bn = bid & 15;           // 0-15

    const size_t a_row0 = (size_t)bm * BM;
    const size_t b_row0 = (size_t)bn * BN;

    // stage one half-tile (128 rows x 64 cols bf16 = 16 KiB): 2 loads/thread.
    // LDS dest linear; global source pre-swizzled (rule #21 both-sides).
    auto stage_half = [&](int buf, int half, int which, int k0) {
        const unsigned short* G = which ? B : A;
        const size_t grow0 = (which ? b_row0 : a_row0) + (size_t)half * 128;
        unsigned short* T = (which ? Bs : As) + buf * 16384 + half * 8192;
#pragma unroll
        for (int i = 0; i < 2; ++i) {
            const int qe    = (i * 512 + tid) * 8;          // elem offset in half
            const int row_h = qe >> 6;                      // 0..127
            const int cswz  = (qe & 63) ^ ((row_h & 7) << 3);
            const unsigned short* src = G + (grow0 + row_h) * IN_F + k0 + cswz;
            unsigned short* dst = T + (i * 512 + (wave << 6)) * 8; // wave-uniform
            __builtin_amdgcn_global_load_lds((gas_void*)src, (las_void*)dst, 16, 0, 0);
        }
    };

    f32x4  acc[8][4] = {};
    bf16x8 a[8][2], b[4][2];

    const int sw   = (lr & 7) << 3;
    const int ksw0 = (lg * 8) ^ sw;
    const int ksw1 = (32 + lg * 8) ^ sw;
    const int arow = (wm * 128 + lr) * 64;
    const int brow = (wn * 64  + lr) * 64;

    auto rdA = [&](int mi, int base) {
        a[mi][0] = *(const bf16x8*)&As[base + arow + mi * 1024 + ksw0];
        a[mi][1] = *(const bf16x8*)&As[base + arow + mi * 1024 + ksw1];
    };
    auto rdB = [&](int ni, int base) {
        b[ni][0] = *(const bf16x8*)&Bs[base + brow + ni * 1024 + ksw0];
        b[ni][1] = *(const bf16x8*)&Bs[base + brow + ni * 1024 + ksw1];
    };

    // ---- prologue: tile0 fully + tile1 A-halves; drain tile0, keep 4 in flight
    stage_half(0, 0, 0, 0);  stage_half(0, 1, 0, 0);
    stage_half(0, 0, 1, 0);  stage_half(0, 1, 1, 0);
    stage_half(1, 0, 0, BK); stage_half(1, 1, 0, BK);
    asm volatile("s_waitcnt vmcnt(4)" ::: "memory");
    __builtin_amdgcn_sched_barrier(0);
    __builtin_amdgcn_s_barrier();
    __builtin_amdgcn_sched_barrier(0);

    for (int t = 0; t < NT; ++t) {
        const int buf  = t & 1;
        const int base = buf * 16384;
        const int bufn = buf ^ 1;

        // ---- Region 1: reads of buf t + B-staging of t+1, MFMA quadrants 1-2.
        // No hard lgkm gates: compiler emits fine-grained lgkmcnt per MFMA use,
        // so reads service under MFMA and waves de-phase within the region.
        rdA(0, base); rdA(1, base); rdA(2, base); rdA(3, base);
        rdB(0, base); rdB(1, base);
        if (t + 1 < NT) stage_half(bufn, 0, 1, (t + 1) * BK);
        QUAD(0, 0);

        rdA(4, base); rdA(5, base); rdA(6, base); rdA(7, base);
        if (t + 1 < NT) stage_half(bufn, 1, 1, (t + 1) * BK);
        QUAD(4, 0);

        rdB(2, base); rdB(3, base);
        __builtin_amdgcn_sched_barrier(0);
        __builtin_amdgcn_s_barrier();                  // #1: As[cur] reads done
        __builtin_amdgcn_sched_barrier(0);

        // ---- Region 2: A-staging of t+2 into freed As[cur], quadrants 3-4.
        if (t + 2 < NT) stage_half(buf, 0, 0, (t + 2) * BK);
        QUAD(4, 2);
        if (t + 2 < NT) stage_half(buf, 1, 0, (t + 2) * BK);
        QUAD(0, 2);

        if (t + 2 < NT) {
            asm volatile("s_waitcnt vmcnt(4)" ::: "memory");
        } else if (t + 1 < NT) {
            asm volatile("s_waitcnt vmcnt(0)" ::: "memory");
        }
        __builtin_amdgcn_sched_barrier(0);
        __builtin_amdgcn_s_barrier();                  // #2: staged halves visible
        __builtin_amdgcn_sched_barrier(0);
    }

    // ---- epilogue: C/D layout col=lane&15, row=(lane>>4)*4+j
    float* Cp = C + (a_row0 + wm * 128) * (size_t)OUT_F + b_row0 + wn * 64;
#pragma unroll
    for (int mi = 0; mi < 8; ++mi)
#pragma unroll
        for (int ni = 0; ni < 4; ++ni)
#pragma unroll
            for (int j = 0; j < 4; ++j)
                Cp[(size_t)(mi * 16 + lg * 4 + j) * OUT_F + ni * 16 + lr] = acc[mi][ni][j];
}

extern "C" void kernel_launch(void* const* d_in, const int* in_sizes, int n_in,
                              void* d_out, int out_size, void* d_ws, size_t ws_size,
                              hipStream_t stream) {
    const float* x      = (const float*)d_in[0];
    const int*   tern   = (const int*)d_in[1];
    const float* scales = (const float*)d_in[2];

    unsigned short* xb = (unsigned short*)d_ws;
    unsigned short* wb = xb + (size_t)TOKENS * IN_F;

    cvt_x_kernel<<<TOKENS * IN_F / 8 / 256, 256, 0, stream>>>(x, xb);
    deq_w_kernel<<<OUT_F * IN_F / 8 / 256, 256, 0, stream>>>(tern, scales, wb);

    dim3 grid((TOKENS / BM) * (OUT_F / BN));   // 32*16 = 512
    gemm_bt_kernel<<<grid, 512, 0, stream>>>(xb, wb, (float*)d_out);
}

// Round 6
// 177.846 us; speedup vs baseline: 1.7789x; 1.5394x over previous
//
#include <hip/hip_runtime.h>

#define TOKENS 8192
#define IN_F   4096
#define OUT_F  4096

#define BM 256
#define BN 256
#define BK 128
#define NT (IN_F / BK)   // 32 K-tiles

typedef __attribute__((ext_vector_type(4))) float  f32x4;
typedef __attribute__((ext_vector_type(4))) int    i32x4;

typedef const __attribute__((address_space(1))) void gas_void;
typedef __attribute__((address_space(3))) void las_void;

// ---------------------------------------------------------------------------
// quant_x: per-token symmetric i8 quantization. One block (256 thr) per row.
// xq[r][i] = rint(x*127/amax_r), dx[r] = amax_r/127.
// ---------------------------------------------------------------------------
__global__ __launch_bounds__(256) void quant_x_kernel(const float* __restrict__ x,
                                                      signed char* __restrict__ xq,
                                                      float* __restrict__ dx) {
    const int row  = blockIdx.x;
    const int tid  = threadIdx.x;
    const int lane = tid & 63;
    const int wv   = tid >> 6;
    const float* xr = x + (size_t)row * IN_F;

    float v[16];
#pragma unroll
    for (int k = 0; k < 4; ++k) {
        f32x4 t = *(const f32x4*)(xr + k * 1024 + tid * 4);
#pragma unroll
        for (int j = 0; j < 4; ++j) v[k * 4 + j] = t[j];
    }
    float m = 0.f;
#pragma unroll
    for (int j = 0; j < 16; ++j) m = fmaxf(m, fabsf(v[j]));
#pragma unroll
    for (int off = 32; off >= 1; off >>= 1) m = fmaxf(m, __shfl_xor(m, off));
    __shared__ float sm[4];
    if (lane == 0) sm[wv] = m;
    __syncthreads();
    m = fmaxf(fmaxf(sm[0], sm[1]), fmaxf(sm[2], sm[3]));

    const float inv = 127.0f / m;
    if (tid == 0) dx[row] = m * (1.0f / 127.0f);

    int* out = (int*)(xq + (size_t)row * IN_F);
#pragma unroll
    for (int k = 0; k < 4; ++k) {
        int p = 0;
#pragma unroll
        for (int j = 0; j < 4; ++j) {
            int q = (int)rintf(v[k * 4 + j] * inv);
            p |= (q & 0xff) << (8 * j);
        }
        out[k * 256 + tid] = p;
    }
}

// ---------------------------------------------------------------------------
// quant_w: per-out-row integer re-scale of ternary weights.
// s_max = max_g scales[o*32+g]; q_g = rint(s_g*127/s_max); wq = tern*q_g;
// dw[o] = s_max/127.  One block per out-row; thread t -> 16 elems, group t/8.
// ---------------------------------------------------------------------------
__global__ __launch_bounds__(256) void quant_w_kernel(const int* __restrict__ tern,
                                                      const float* __restrict__ scales,
                                                      signed char* __restrict__ wq,
                                                      float* __restrict__ dw) {
    const int o   = blockIdx.x;
    const int tid = threadIdx.x;
    const float* sr = scales + o * 32;

    float smax = 0.f;
#pragma unroll
    for (int g = 0; g < 32; ++g) smax = fmaxf(smax, sr[g]);   // uniform -> s_loads
    if (tid == 0) dw[o] = smax * (1.0f / 127.0f);

    const int   g  = tid >> 3;                                 // group of this thread's 16 elems
    const int   iq = (int)rintf(sr[g] * (127.0f / smax));

    const i32x4* tp = (const i32x4*)(tern + (size_t)o * IN_F + tid * 16);
    i32x4 out;
#pragma unroll
    for (int k = 0; k < 4; ++k) {
        i32x4 t = tp[k];
        int p = 0;
#pragma unroll
        for (int j = 0; j < 4; ++j) p |= ((t[j] * iq) & 0xff) << (8 * j);
        out[k] = p;
    }
    *(i32x4*)(wq + (size_t)o * IN_F + tid * 16) = out;
}

// ---------------------------------------------------------------------------
// C[M][N] = (xq[M][K] . wq[N][K]^T) * dx[m] * dw[n],  i8 MFMA, i32 acc.
// 256x256 tile, BK=128, 8 waves (2M x 4N), per-wave 128x64.
// r5-verified two-barrier schedule (reads' compiler lgkm waits precede the
// barrier preceding each overwrite; counted vmcnt(4); T2 swizzle shift 4;
// T5 setprio).  LDS: [2][256][128] i8 x2 = 128 KiB.
// Swizzle involution: LDS(row,col) = G(row, col ^ ((row&7)<<4)).
// ---------------------------------------------------------------------------

#define QUAD(MI0, NI0)                                                         \
  do {                                                                         \
    __builtin_amdgcn_s_setprio(1);                                             \
    _Pragma("unroll") for (int mi = 0; mi < 4; ++mi)                           \
      _Pragma("unroll") for (int ni = 0; ni < 2; ++ni)                         \
        _Pragma("unroll") for (int kk = 0; kk < 2; ++kk)                       \
          acc[(MI0)+mi][(NI0)+ni] = __builtin_amdgcn_mfma_i32_16x16x64_i8(     \
              a[(MI0)+mi][kk], b[(NI0)+ni][kk], acc[(MI0)+mi][(NI0)+ni],0,0,0);\
    __builtin_amdgcn_s_setprio(0);                                             \
  } while (0)

__global__ __launch_bounds__(512, 2) void gemm_i8_kernel(
        const signed char* __restrict__ A,
        const signed char* __restrict__ B,
        const float* __restrict__ dX,
        const float* __restrict__ dW,
        float* __restrict__ C) {
    __shared__ __align__(16) signed char As[2 * 256 * 128];
    __shared__ __align__(16) signed char Bs[2 * 256 * 128];

    const int tid  = threadIdx.x;
    const int wave = tid >> 6;
    const int lane = tid & 63;
    const int wm   = wave >> 2;        // 0-1
    const int wn   = wave & 3;         // 0-3
    const int lg   = lane >> 4;        // 0-3
    const int lr   = lane & 15;        // 0-15

    int bid = blockIdx.x;
    bid = (bid & 7) * (512 >> 3) + (bid >> 3);   // XCD swizzle, 512%8==0
    const int bm = bid >> 4;           // 0-31
    const int bn = bid & 15;           // 0-15

    const size_t a_row0 = (size_t)bm * BM;
    const size_t b_row0 = (size_t)bn * BN;

    // stage one half-tile (128 rows x 128 i8 = 16 KiB): 2 loads/thread.
    auto stage_half = [&](int buf, int half, int which, int k0) {
        const signed char* G = which ? B : A;
        const size_t grow0 = (which ? b_row0 : a_row0) + (size_t)half * 128;
        signed char* T = (which ? Bs : As) + buf * 32768 + half * 16384;
#pragma unroll
        for (int i = 0; i < 2; ++i) {
            const int qe    = (i * 512 + tid) * 16;         // byte offset in half
            const int row_h = qe >> 7;                      // 0..127
            const int cswz  = (qe & 127) ^ ((row_h & 7) << 4);
            const signed char* src = G + (grow0 + row_h) * IN_F + k0 + cswz;
            signed char* dst = T + i * 8192 + wave * 1024;  // wave-uniform base
            __builtin_amdgcn_global_load_lds((gas_void*)src, (las_void*)dst, 16, 0, 0);
        }
    };

    i32x4 acc[8][4] = {};
    i32x4 a[8][2], b[4][2];

    const int sw16 = (lr & 7) << 4;
    const int arow = (wm * 128 + lr) * 128;
    const int brow = (wn * 64  + lr) * 128;

    auto rdA = [&](int mi, int base) {
        a[mi][0] = *(const i32x4*)&As[base + arow + mi * 2048 + ((lg * 16) ^ sw16)];
        a[mi][1] = *(const i32x4*)&As[base + arow + mi * 2048 + ((64 + lg * 16) ^ sw16)];
    };
    auto rdB = [&](int ni, int base) {
        b[ni][0] = *(const i32x4*)&Bs[base + brow + ni * 2048 + ((lg * 16) ^ sw16)];
        b[ni][1] = *(const i32x4*)&Bs[base + brow + ni * 2048 + ((64 + lg * 16) ^ sw16)];
    };

    // ---- prologue: tile0 fully + tile1 A-halves; drain tile0, keep 4 in flight
    stage_half(0, 0, 0, 0);  stage_half(0, 1, 0, 0);
    stage_half(0, 0, 1, 0);  stage_half(0, 1, 1, 0);
    stage_half(1, 0, 0, BK); stage_half(1, 1, 0, BK);
    asm volatile("s_waitcnt vmcnt(4)" ::: "memory");
    __builtin_amdgcn_sched_barrier(0);
    __builtin_amdgcn_s_barrier();
    __builtin_amdgcn_sched_barrier(0);

    for (int t = 0; t < NT; ++t) {
        const int buf  = t & 1;
        const int base = buf * 32768;
        const int bufn = buf ^ 1;

        // ---- Region 1: all ds_reads of buf t + B-staging of t+1, QUADs 1-2.
        rdA(0, base); rdA(1, base); rdA(2, base); rdA(3, base);
        rdB(0, base); rdB(1, base);
        if (t + 1 < NT) stage_half(bufn, 0, 1, (t + 1) * BK);
        QUAD(0, 0);

        rdA(4, base); rdA(5, base); rdA(6, base); rdA(7, base);
        if (t + 1 < NT) stage_half(bufn, 1, 1, (t + 1) * BK);
        QUAD(4, 0);

        rdB(2, base); rdB(3, base);
        __builtin_amdgcn_sched_barrier(0);
        __builtin_amdgcn_s_barrier();                  // #1: As[cur] reads done
        __builtin_amdgcn_sched_barrier(0);

        // ---- Region 2: A-staging of t+2 into freed As[cur], QUADs 3-4.
        if (t + 2 < NT) stage_half(buf, 0, 0, (t + 2) * BK);
        QUAD(4, 2);
        if (t + 2 < NT) stage_half(buf, 1, 0, (t + 2) * BK);
        QUAD(0, 2);

        if (t + 2 < NT) {
            asm volatile("s_waitcnt vmcnt(4)" ::: "memory");
        } else if (t + 1 < NT) {
            asm volatile("s_waitcnt vmcnt(0)" ::: "memory");
        }
        __builtin_amdgcn_sched_barrier(0);
        __builtin_amdgcn_s_barrier();                  // #2: staged halves visible
        __builtin_amdgcn_sched_barrier(0);
    }

    // ---- epilogue: out = acc * dx[row] * dw[col]; C/D layout col=lane&15,
    // row=(lane>>4)*4+j (dtype-independent, i8-verified m121-128)
    float dwc[4];
#pragma unroll
    for (int ni = 0; ni < 4; ++ni) dwc[ni] = dW[b_row0 + wn * 64 + ni * 16 + lr];

    float* Cp = C + (a_row0 + wm * 128) * (size_t)OUT_F + b_row0 + wn * 64;
#pragma unroll
    for (int mi = 0; mi < 8; ++mi) {
#pragma unroll
        for (int j = 0; j < 4; ++j) {
            const int r = mi * 16 + lg * 4 + j;
            const float dxr = dX[a_row0 + wm * 128 + r];
#pragma unroll
            for (int ni = 0; ni < 4; ++ni)
                Cp[(size_t)r * OUT_F + ni * 16 + lr] =
                    (float)acc[mi][ni][j] * dxr * dwc[ni];
        }
    }
}

extern "C" void kernel_launch(void* const* d_in, const int* in_sizes, int n_in,
                              void* d_out, int out_size, void* d_ws, size_t ws_size,
                              hipStream_t stream) {
    const float* x      = (const float*)d_in[0];
    const int*   tern   = (const int*)d_in[1];
    const float* scales = (const float*)d_in[2];

    signed char* xq = (signed char*)d_ws;                          // 33.6 MB
    signed char* wq = xq + (size_t)TOKENS * IN_F;                  // 16.8 MB
    float*       dx = (float*)(wq + (size_t)OUT_F * IN_F);         // 32 KB
    float*       dw = dx + TOKENS;                                 // 16 KB

    quant_x_kernel<<<TOKENS, 256, 0, stream>>>(x, xq, dx);
    quant_w_kernel<<<OUT_F, 256, 0, stream>>>(tern, scales, wq, dw);

    dim3 grid((TOKENS / BM) * (OUT_F / BN));   // 512
    gemm_i8_kernel<<<grid, 512, 0, stream>>>(xq, wq, dx, dw, (float*)d_out);
}